// Round 1
// baseline (3271.851 us; speedup 1.0000x reference)
//
#include <hip/hip_runtime.h>
#include <math.h>

#define Lt 512   // timesteps
#define Bn 128   // batch
#define Dd 512   // input dim
#define Hh 512   // hidden dim
#define BH (Bn * Hh)

typedef __attribute__((ext_vector_type(4))) float f32x4;
typedef __attribute__((ext_vector_type(8))) __bf16 bf16x8;
typedef __attribute__((ext_vector_type(8))) unsigned short u16x8;
typedef __attribute__((ext_vector_type(4))) unsigned int u32x4;

#define MFMA16 __builtin_amdgcn_mfma_f32_16x16x32_bf16

__device__ __forceinline__ float bf2f(unsigned short s) {
    return __uint_as_float(((unsigned)s) << 16);
}
__device__ __forceinline__ unsigned short f2bf_rne(float f) {
    unsigned u = __float_as_uint(f);
    u = (u + 0x7FFFu + ((u >> 16) & 1u)) >> 16;
    return (unsigned short)u;
}
// tanh via hw exp+rcp; saturates exactly at +/-1, NaN-free
__device__ __forceinline__ float tanh_fast(float z) {
    float e = __expf(2.f * z);
    return 1.f - 2.f * __builtin_amdgcn_rcpf(e + 1.f);
}
// result = (top16(b)<<16) | top16(a)
__device__ __forceinline__ unsigned pack_hi16(unsigned a, unsigned b) {
    return __builtin_amdgcn_perm(b, a, 0x07060302u);
}
// result = (low16(b)<<16) | low16(a)
__device__ __forceinline__ unsigned pack_lo16(unsigned a, unsigned b) {
    return __builtin_amdgcn_perm(b, a, 0x05040100u);
}

__global__ void zero_flags_kernel(unsigned* __restrict__ flags) {
    int i = blockIdx.x * 256 + threadIdx.x;
    if (i < 256) flags[i] = 0;
}

// stage 16 rows x 512 cols of W (row stride = `stride`) into LDS as bf16 hi/lo
__device__ __forceinline__ void stage_wslice(const float* __restrict__ W, int j0g,
                                             int stride, unsigned short* hiA,
                                             unsigned short* loA, int lane) {
    #pragma unroll 4
    for (int it = 0; it < 32; ++it) {
        int idx = (it * 64 + lane) * 4;
        int j = idx >> 9;
        int k = idx & 511;
        float4 w = *(const float4*)(W + (size_t)(j0g + j) * stride + k);
        int base = j * 520 + k;
        unsigned short s0 = f2bf_rne(w.x); hiA[base + 0] = s0; loA[base + 0] = f2bf_rne(w.x - bf2f(s0));
        unsigned short s1 = f2bf_rne(w.y); hiA[base + 1] = s1; loA[base + 1] = f2bf_rne(w.y - bf2f(s1));
        unsigned short s2 = f2bf_rne(w.z); hiA[base + 2] = s2; loA[base + 2] = f2bf_rne(w.z - bf2f(s2));
        unsigned short s3 = f2bf_rne(w.w); hiA[base + 3] = s3; loA[base + 3] = f2bf_rne(w.w - bf2f(s3));
    }
}

// ---------------------------------------------------------------------------
// Kernel 1: xproj[m, j] = x[m,:] . Wx[j,:] + bx[j] + bh[j], m = l*Bn+b (65536
// rows). Written INTO out[0 .. L*B*H) — the recurrence reads each tile as xp
// and then overwrites it with h_t (same wg, read-before-write, no hazard).
// 2048 wgs x 1 wave; wg = (class=blk&7, jg, slab). All 32 jg of one 1024-row
// slab share blk&7 -> same XCD under rr dispatch -> x fetched from HBM ~once.
// Per-wave math identical to the proven xp phase (hi/lo bf16, 3 MFMAs).
// ---------------------------------------------------------------------------
__global__ __launch_bounds__(64, 1) void xproj_kernel(
    const float* __restrict__ x, const float* __restrict__ Wx,
    const float* __restrict__ bx, const float* __restrict__ bh,
    float* __restrict__ out) {

    __shared__ unsigned short WHi[16 * 520], WLo[16 * 520];

    const int lane = threadIdx.x;
    const int cls  = blockIdx.x & 7;        // XCD class under rr dispatch
    const int idx  = blockIdx.x >> 3;       // 0..255
    const int jg   = idx & 31;              // 32 j-slices of 16
    const int slab = cls * 8 + (idx >> 5);  // 0..63, 1024 rows each
    const int j0g  = jg * 16;

    stage_wslice(Wx, j0g, Dd, WHi, WLo, lane);
    __syncthreads();

    const int rw = lane & 15;
    const int quad = lane >> 4;
    const unsigned short* HiR = WHi + rw * 520;
    const unsigned short* LoR = WLo + rw * 520;
    const float bsum = bx[j0g + rw] + bh[j0g + rw];
    const int row0 = slab * 1024;

    for (int rt = 0; rt < 64; ++rt) {
        const int r0 = row0 + rt * 16;
        f32x4 aHH = {0.f, 0.f, 0.f, 0.f};
        f32x4 aHL = {0.f, 0.f, 0.f, 0.f};
        f32x4 aLH = {0.f, 0.f, 0.f, 0.f};
        const float* xrow = x + (size_t)(r0 + rw) * Dd;
        #pragma unroll
        for (int c = 0; c < 16; ++c) {
            int kk = c * 32 + quad * 8;
            float4 v0 = *(const float4*)(xrow + kk);
            float4 v1 = *(const float4*)(xrow + kk + 4);
            unsigned u0 = __float_as_uint(v0.x), u1 = __float_as_uint(v0.y);
            unsigned u2 = __float_as_uint(v0.z), u3 = __float_as_uint(v0.w);
            unsigned u4 = __float_as_uint(v1.x), u5 = __float_as_uint(v1.y);
            unsigned u6 = __float_as_uint(v1.z), u7 = __float_as_uint(v1.w);
            u32x4 hi4 = {pack_hi16(u0, u1), pack_hi16(u2, u3),
                         pack_hi16(u4, u5), pack_hi16(u6, u7)};
            float l0 = v0.x - __uint_as_float(u0 & 0xFFFF0000u);
            float l1 = v0.y - __uint_as_float(u1 & 0xFFFF0000u);
            float l2 = v0.z - __uint_as_float(u2 & 0xFFFF0000u);
            float l3 = v0.w - __uint_as_float(u3 & 0xFFFF0000u);
            float l4 = v1.x - __uint_as_float(u4 & 0xFFFF0000u);
            float l5 = v1.y - __uint_as_float(u5 & 0xFFFF0000u);
            float l6 = v1.z - __uint_as_float(u6 & 0xFFFF0000u);
            float l7 = v1.w - __uint_as_float(u7 & 0xFFFF0000u);
            u32x4 lo4 = {pack_hi16(__float_as_uint(l0), __float_as_uint(l1)),
                         pack_hi16(__float_as_uint(l2), __float_as_uint(l3)),
                         pack_hi16(__float_as_uint(l4), __float_as_uint(l5)),
                         pack_hi16(__float_as_uint(l6), __float_as_uint(l7))};
            bf16x8 aH = __builtin_bit_cast(bf16x8, hi4);
            bf16x8 aL = __builtin_bit_cast(bf16x8, lo4);
            bf16x8 bH = __builtin_bit_cast(bf16x8, *(const u16x8*)(HiR + kk));
            bf16x8 bL = __builtin_bit_cast(bf16x8, *(const u16x8*)(LoR + kk));
            aHH = MFMA16(aH, bH, aHH, 0, 0, 0);
            aHL = MFMA16(aH, bL, aHL, 0, 0, 0);
            aLH = MFMA16(aL, bH, aLH, 0, 0, 0);
        }
        f32x4 acc = aHH + aHL + aLH;
        // C/D layout: col=lane&15 (j), row=quad*4+r (m)
        #pragma unroll
        for (int r = 0; r < 4; ++r) {
            int m = r0 + quad * 4 + r;
            out[(size_t)m * Hh + (j0g + rw)] = acc[r] + bsum;
        }
    }
}

// ---------------------------------------------------------------------------
// Kernel 2: recurrence only. 256 wgs x 64 threads (1 wave), wg=(bg,jg) as
// before. Per step: prefetch 1KB xp tile from out[t] (issued before the poll,
// latency hidden under the spin) -> poll -> h_{t-1}*Wh^T -> tanh(acc+xp) ->
// publish. The xp phase / Wx staging / x HBM streaming are gone from the
// serial chain. Handoff protocol (packed hi|lo u32, double-buffered hpk,
// relaxed agent atomics, monotonic flags) is unchanged from the verified
// version. Deadlock-free: 256 one-wave wgs co-resident on 256 CUs.
// ---------------------------------------------------------------------------
__global__ __launch_bounds__(64, 1) void rnn_rec_kernel(
    const float* __restrict__ h0in, const float* __restrict__ Wh,
    float* __restrict__ out, unsigned* __restrict__ hpk, unsigned* flags) {

    __shared__ unsigned short WhHi[16 * 520], WhLo[16 * 520];

    const int lane = threadIdx.x;
    const int bg = blockIdx.x & 7;    // same bg -> same XCD under rr dispatch
    const int jg = blockIdx.x >> 3;
    const int b0g = bg * 16;
    const int j0g = jg * 16;

    stage_wslice(Wh, j0g, Hh, WhHi, WhLo, lane);
    __syncthreads();  // one-time only

    const int rw = lane & 15;
    const int quad = lane >> 4;
    const unsigned short* WhHiR = WhHi + rw * 520;
    const unsigned short* WhLoR = WhLo + rw * 520;

    // ---- prologue: publish h0 tile into buf1 (read by step 0) ----
    #pragma unroll
    for (int r = 0; r < 4; ++r) {
        int b = b0g + quad * 4 + r;
        float v = h0in[(size_t)b * Hh + (j0g + rw)];
        unsigned u = __float_as_uint(v);
        unsigned hb = u >> 16;  // trunc split
        unsigned lb = __float_as_uint(v - __uint_as_float(u & 0xFFFF0000u)) >> 16;
        __hip_atomic_store(hpk + BH + (size_t)b * Hh + (j0g + rw),
                           (hb << 16) | lb, __ATOMIC_RELAXED,
                           __HIP_MEMORY_SCOPE_AGENT);
    }
    asm volatile("s_waitcnt vmcnt(0)" ::: "memory");
    if (lane == 0) {
        __hip_atomic_store(&flags[bg * 32 + jg], 1u, __ATOMIC_RELAXED,
                           __HIP_MEMORY_SCOPE_AGENT);
    }

    for (int t = 0; t < Lt; ++t) {
        // ---- xp prefetch: own 16x16 tile of out[t] (written by xproj_kernel).
        // Issued before the poll; completes under the spin. Overwritten by h_t
        // below by this same wg only — no cross-wg hazard.
        float xpv[4];
        {
            const float* xprow = out + (size_t)t * BH;
            #pragma unroll
            for (int r = 0; r < 4; ++r)
                xpv[r] = xprow[(size_t)(b0g + quad * 4 + r) * Hh + (j0g + rw)];
        }

        // ---- wait for h_{t-1}: all 32 producers of this bg ----
        {
            const unsigned tgt = (unsigned)t + 1u;
            while (true) {
                unsigned v = __hip_atomic_load(&flags[bg * 32 + (lane & 31)],
                                               __ATOMIC_RELAXED,
                                               __HIP_MEMORY_SCOPE_AGENT);
                if (__ballot(v >= tgt) == 0xFFFFFFFFFFFFFFFFull) break;
            }
        }

        // ---- h phase: h_{t-1} * Wh^T ----
        f32x4 aHH = {0.f, 0.f, 0.f, 0.f};
        f32x4 aHL = {0.f, 0.f, 0.f, 0.f};
        f32x4 aLH = {0.f, 0.f, 0.f, 0.f};
        const unsigned* hrow =
            hpk + (size_t)((t + 1) & 1) * BH + (size_t)(b0g + rw) * Hh;
        #pragma unroll
        for (int c = 0; c < 16; ++c) {
            int kk = c * 32 + quad * 8;
            unsigned long long p0 = __hip_atomic_load(
                (const unsigned long long*)(hrow + kk + 0),
                __ATOMIC_RELAXED, __HIP_MEMORY_SCOPE_AGENT);
            unsigned long long p1 = __hip_atomic_load(
                (const unsigned long long*)(hrow + kk + 2),
                __ATOMIC_RELAXED, __HIP_MEMORY_SCOPE_AGENT);
            unsigned long long p2 = __hip_atomic_load(
                (const unsigned long long*)(hrow + kk + 4),
                __ATOMIC_RELAXED, __HIP_MEMORY_SCOPE_AGENT);
            unsigned long long p3 = __hip_atomic_load(
                (const unsigned long long*)(hrow + kk + 6),
                __ATOMIC_RELAXED, __HIP_MEMORY_SCOPE_AGENT);
            unsigned q0 = (unsigned)p0, q1 = (unsigned)(p0 >> 32);
            unsigned q2 = (unsigned)p1, q3 = (unsigned)(p1 >> 32);
            unsigned q4 = (unsigned)p2, q5 = (unsigned)(p2 >> 32);
            unsigned q6 = (unsigned)p3, q7 = (unsigned)(p3 >> 32);
            u32x4 hi4 = {pack_hi16(q0, q1), pack_hi16(q2, q3),
                         pack_hi16(q4, q5), pack_hi16(q6, q7)};
            u32x4 lo4 = {pack_lo16(q0, q1), pack_lo16(q2, q3),
                         pack_lo16(q4, q5), pack_lo16(q6, q7)};
            bf16x8 aH = __builtin_bit_cast(bf16x8, hi4);
            bf16x8 aL = __builtin_bit_cast(bf16x8, lo4);
            bf16x8 bH = __builtin_bit_cast(bf16x8, *(const u16x8*)(WhHiR + kk));
            bf16x8 bL = __builtin_bit_cast(bf16x8, *(const u16x8*)(WhLoR + kk));
            aHH = MFMA16(aH, bH, aHH, 0, 0, 0);
            aHL = MFMA16(aH, bL, aHL, 0, 0, 0);
            aLH = MFMA16(aL, bH, aLH, 0, 0, 0);
        }

        f32x4 acc = aHH + aHL + aLH;

        // ---- epilogue: C/D layout col=lane&15 (j), row=quad*4+r (b) ----
        float hv[4];
        #pragma unroll
        for (int r = 0; r < 4; ++r) hv[r] = tanh_fast(acc[r] + xpv[r]);

        unsigned* hw = hpk + (size_t)(t & 1) * BH;
        #pragma unroll
        for (int r = 0; r < 4; ++r) {
            int b = b0g + quad * 4 + r;
            unsigned u = __float_as_uint(hv[r]);
            unsigned hb = u >> 16;
            unsigned lb =
                __float_as_uint(hv[r] - __uint_as_float(u & 0xFFFF0000u)) >> 16;
            __hip_atomic_store(hw + (size_t)b * Hh + (j0g + rw), (hb << 16) | lb,
                               __ATOMIC_RELAXED, __HIP_MEMORY_SCOPE_AGENT);
        }
        asm volatile("s_waitcnt vmcnt(0)" ::: "memory");
        if (lane == 0 && t + 1 < Lt) {
            __hip_atomic_store(&flags[bg * 32 + jg], (unsigned)(t + 2),
                               __ATOMIC_RELAXED, __HIP_MEMORY_SCOPE_AGENT);
        }

        // out stores after the flag — not on anyone's critical path
        #pragma unroll
        for (int r = 0; r < 4; ++r) {
            int b = b0g + quad * 4 + r;
            out[((size_t)t * Bn + b) * Hh + (j0g + rw)] = hv[r];
        }
        if (t == Lt - 1) {
            #pragma unroll
            for (int r = 0; r < 4; ++r) {
                int b = b0g + quad * 4 + r;
                out[(size_t)Lt * BH + (size_t)b * Hh + (j0g + rw)] = hv[r];
            }
        }
    }
}

extern "C" void kernel_launch(void* const* d_in, const int* in_sizes, int n_in,
                              void* d_out, int out_size, void* d_ws, size_t ws_size,
                              hipStream_t stream) {
    const float* x    = (const float*)d_in[0];  // [L,B,D]
    const float* h0   = (const float*)d_in[1];  // [B,H]
    const float* Wx_w = (const float*)d_in[2];  // [H,D]
    const float* Wx_b = (const float*)d_in[3];  // [H]
    const float* Wh_w = (const float*)d_in[4];  // [H,H]
    const float* Wh_b = (const float*)d_in[5];  // [H]
    float* out = (float*)d_out;                 // hAll [L,B,H] ++ h_last [B,H]

    unsigned* hpk   = (unsigned*)d_ws;          // 2 x [B][H] packed (hi|lo), 512 KB
    unsigned* flags = hpk + 2 * BH;             // [8][32] monotonic counters

    zero_flags_kernel<<<1, 256, 0, stream>>>(flags);
    // Pass 1: xproj (+ both biases) into out[0 .. L*B*H)
    xproj_kernel<<<2048, 64, 0, stream>>>(x, Wx_w, Wx_b, Wh_b, out);
    // Pass 2: recurrence, reads xp from out and overwrites with h_t
    rnn_rec_kernel<<<256, 64, 0, stream>>>(h0, Wh_w, out, hpk, flags);
}

// Round 2
// 2577.940 us; speedup vs baseline: 1.2692x; 1.2692x over previous
//
#include <hip/hip_runtime.h>
#include <math.h>

#define Lt 512   // timesteps
#define Bn 128   // batch
#define Dd 512   // input dim
#define Hh 512   // hidden dim
#define BH (Bn * Hh)

typedef __attribute__((ext_vector_type(4))) float f32x4;
typedef __attribute__((ext_vector_type(8))) __bf16 bf16x8;
typedef __attribute__((ext_vector_type(8))) unsigned short u16x8;
typedef __attribute__((ext_vector_type(4))) unsigned int u32x4;

#define MFMA16 __builtin_amdgcn_mfma_f32_16x16x32_bf16

__device__ __forceinline__ float bf2f(unsigned short s) {
    return __uint_as_float(((unsigned)s) << 16);
}
__device__ __forceinline__ unsigned short f2bf_rne(float f) {
    unsigned u = __float_as_uint(f);
    u = (u + 0x7FFFu + ((u >> 16) & 1u)) >> 16;
    return (unsigned short)u;
}
// tanh via hw exp+rcp; saturates exactly at +/-1, NaN-free
__device__ __forceinline__ float tanh_fast(float z) {
    float e = __expf(2.f * z);
    return 1.f - 2.f * __builtin_amdgcn_rcpf(e + 1.f);
}
// result = (top16(b)<<16) | top16(a)
__device__ __forceinline__ unsigned pack_hi16(unsigned a, unsigned b) {
    return __builtin_amdgcn_perm(b, a, 0x07060302u);
}
// result = (low16(b)<<16) | low16(a)
__device__ __forceinline__ unsigned pack_lo16(unsigned a, unsigned b) {
    return __builtin_amdgcn_perm(b, a, 0x05040100u);
}
// XOR-swizzled LDS index (u16 units) for a [16][512] u16 tile.
// Row stride 512 u16 = 1KB; XOR of bits 3..5 by (row&7) spreads the 16B
// granules of the 16 rows across 8 bank-quads -> 2-way max on ds_read_b128.
__device__ __forceinline__ int swzi(int r_, int k_) {
    return (r_ << 9) + (k_ ^ ((r_ & 7) << 3));
}

__global__ void zero_flags_kernel(unsigned* __restrict__ flags) {
    int i = blockIdx.x * 256 + threadIdx.x;
    if (i < 256) flags[i] = 0;
}

// Preload one wave's 16-row W j-slice as bf16 hi/lo MFMA B-fragments into
// VGPRs: wH[c]/wL[c] hold W[row][c*32+quad*8 .. +8]. 128 VGPRs total.
__device__ __forceinline__ void preload_w(const float* __restrict__ W, int row,
                                          int quad, bf16x8* wH, bf16x8* wL) {
    const float* wr = W + (size_t)row * 512;
    #pragma unroll
    for (int c = 0; c < 16; ++c) {
        int kk = c * 32 + quad * 8;
        float4 v0 = *(const float4*)(wr + kk);
        float4 v1 = *(const float4*)(wr + kk + 4);
        float vv[8] = {v0.x, v0.y, v0.z, v0.w, v1.x, v1.y, v1.z, v1.w};
        u16x8 hh, ll;
        #pragma unroll
        for (int e = 0; e < 8; ++e) {
            unsigned short s = f2bf_rne(vv[e]);
            hh[e] = s;
            ll[e] = f2bf_rne(vv[e] - bf2f(s));
        }
        wH[c] = __builtin_bit_cast(bf16x8, hh);
        wL[c] = __builtin_bit_cast(bf16x8, ll);
    }
}

// ---------------------------------------------------------------------------
// Kernel 1: xproj = x . Wx^T + bx + bh, written into out[0 .. L*B*H).
// 512 wgs x 256 thr (4 waves). wg = (jgrp = blk>>6, mslab = blk&63); wave w
// owns j-slice j0 = (jgrp*4+w)*16 with its Wx hi/lo fragments in 128 VGPRs.
// Per 16-row m-tile: 256 threads stage x-tile (16x512 fp32) into swizzled
// LDS as trunc-split hi/lo bf16 (shared by all 4 waves), then each wave runs
// 16 c-steps x 3 MFMA. blk%8 = mslab%8 -> the 8 jgrp wgs of one slab share
// an XCD under rr dispatch -> x fetched from HBM ~once.
// ---------------------------------------------------------------------------
__global__ __launch_bounds__(256, 2) void xproj_kernel(
    const float* __restrict__ x, const float* __restrict__ Wx,
    const float* __restrict__ bx, const float* __restrict__ bh,
    float* __restrict__ out) {

    __shared__ unsigned short XH[16 * 512], XL[16 * 512];

    const int tid = threadIdx.x;
    const int wave = tid >> 6;
    const int lane = tid & 63;
    const int rw = lane & 15;
    const int quad = (lane >> 4) & 3;
    const int jgrp = blockIdx.x >> 6;   // 0..7
    const int mslab = blockIdx.x & 63;  // 0..63; XCD = blk%8 = mslab%8
    const int j0 = (jgrp * 4 + wave) * 16;

    bf16x8 wxH[16], wxL[16];
    preload_w(Wx, j0 + rw, quad, wxH, wxL);
    const float bsum = bx[j0 + rw] + bh[j0 + rw];

    const int r = tid >> 4;           // 0..15: staged row
    const int cf0 = (tid & 15) * 32;  // 32-float column chunk

    for (int it = 0; it < 64; ++it) {
        const int m0 = mslab * 1024 + it * 16;
        // ---- stage x[m0..m0+16][:] as hi/lo bf16 into swizzled LDS ----
        {
            const float* xr = x + (size_t)(m0 + r) * Dd + cf0;
            float4 v[8];
            #pragma unroll
            for (int q = 0; q < 8; ++q) v[q] = *(const float4*)(xr + q * 4);
            #pragma unroll
            for (int g = 0; g < 4; ++g) {
                float4 va = v[2 * g], vb = v[2 * g + 1];
                unsigned ua0 = __float_as_uint(va.x), ua1 = __float_as_uint(va.y);
                unsigned ua2 = __float_as_uint(va.z), ua3 = __float_as_uint(va.w);
                unsigned ub0 = __float_as_uint(vb.x), ub1 = __float_as_uint(vb.y);
                unsigned ub2 = __float_as_uint(vb.z), ub3 = __float_as_uint(vb.w);
                u32x4 Hq = {pack_hi16(ua0, ua1), pack_hi16(ua2, ua3),
                            pack_hi16(ub0, ub1), pack_hi16(ub2, ub3)};
                float l0 = va.x - __uint_as_float(ua0 & 0xFFFF0000u);
                float l1 = va.y - __uint_as_float(ua1 & 0xFFFF0000u);
                float l2 = va.z - __uint_as_float(ua2 & 0xFFFF0000u);
                float l3 = va.w - __uint_as_float(ua3 & 0xFFFF0000u);
                float l4 = vb.x - __uint_as_float(ub0 & 0xFFFF0000u);
                float l5 = vb.y - __uint_as_float(ub1 & 0xFFFF0000u);
                float l6 = vb.z - __uint_as_float(ub2 & 0xFFFF0000u);
                float l7 = vb.w - __uint_as_float(ub3 & 0xFFFF0000u);
                u32x4 Lq = {pack_hi16(__float_as_uint(l0), __float_as_uint(l1)),
                            pack_hi16(__float_as_uint(l2), __float_as_uint(l3)),
                            pack_hi16(__float_as_uint(l4), __float_as_uint(l5)),
                            pack_hi16(__float_as_uint(l6), __float_as_uint(l7))};
                int idx = swzi(r, cf0 + g * 8);
                *(u32x4*)&XH[idx] = Hq;
                *(u32x4*)&XL[idx] = Lq;
            }
        }
        __syncthreads();
        // ---- MFMA: 16 c-steps, B from VGPRs ----
        f32x4 aHH = {0.f, 0.f, 0.f, 0.f};
        f32x4 aHL = {0.f, 0.f, 0.f, 0.f};
        f32x4 aLH = {0.f, 0.f, 0.f, 0.f};
        #pragma unroll
        for (int c = 0; c < 16; ++c) {
            int kk = c * 32 + quad * 8;
            bf16x8 aH = __builtin_bit_cast(bf16x8, *(const u16x8*)&XH[swzi(rw, kk)]);
            bf16x8 aL = __builtin_bit_cast(bf16x8, *(const u16x8*)&XL[swzi(rw, kk)]);
            aHH = MFMA16(aH, wxH[c], aHH, 0, 0, 0);
            aHL = MFMA16(aH, wxL[c], aHL, 0, 0, 0);
            aLH = MFMA16(aL, wxH[c], aLH, 0, 0, 0);
        }
        f32x4 acc = aHH + aHL + aLH;
        // C/D layout: col=lane&15 (j), row=quad*4+rr (m)
        #pragma unroll
        for (int rr = 0; rr < 4; ++rr) {
            int m = m0 + quad * 4 + rr;
            out[(size_t)m * Hh + (j0 + rw)] = acc[rr] + bsum;
        }
        __syncthreads();  // protect LDS overwrite next tile
    }
}

// ---------------------------------------------------------------------------
// Kernel 2: recurrence. 64 wgs x 256 thr (4 waves); wg = (bg = blk&7,
// jgrp = blk>>3). Wave w owns j-slice (jgrp*4+w)*16 with Wh hi/lo in 128
// VGPRs. Per step: poll 8 flags -> xp tile loads (post-poll: no vmcnt
// poisoning) -> cooperative 32KB h load from IC (ONCE per wg, 4x less IC
// traffic than 1-wave wgs) decoded into swizzled LDS hi/lo -> barrier ->
// 16 c-steps x 3 MFMA per wave -> tanh(acc+xp) -> publish (packed u32,
// vmcnt(0) -> barrier -> flag). Handoff protocol identical to the verified
// version; 64 one-wg-per-CU wgs co-resident -> spin-safe.
// ---------------------------------------------------------------------------
__global__ __launch_bounds__(256, 1) void rnn_rec4_kernel(
    const float* __restrict__ h0in, const float* __restrict__ Wh,
    float* __restrict__ out, unsigned* __restrict__ hpk, unsigned* flags) {

    __shared__ unsigned short HHi[16 * 512], HLo[16 * 512];

    const int tid = threadIdx.x;
    const int wave = tid >> 6;
    const int lane = tid & 63;
    const int rw = lane & 15;
    const int quad = (lane >> 4) & 3;
    const int bg = blockIdx.x & 7;    // same bg -> same XCD under rr dispatch
    const int jgrp = blockIdx.x >> 3; // 0..7
    const int b0 = bg * 16;
    const int j0 = (jgrp * 4 + wave) * 16;

    bf16x8 whH[16], whL[16];
    preload_w(Wh, j0 + rw, quad, whH, whL);

    // ---- prologue: publish h0 tile into buf1 (read by step 0) ----
    #pragma unroll
    for (int rr = 0; rr < 4; ++rr) {
        int b = b0 + quad * 4 + rr;
        float v = h0in[(size_t)b * Hh + (j0 + rw)];
        unsigned u = __float_as_uint(v);
        unsigned hb = u >> 16;  // trunc split
        unsigned lb = __float_as_uint(v - __uint_as_float(u & 0xFFFF0000u)) >> 16;
        __hip_atomic_store(hpk + BH + (size_t)b * Hh + (j0 + rw), (hb << 16) | lb,
                           __ATOMIC_RELAXED, __HIP_MEMORY_SCOPE_AGENT);
    }
    asm volatile("s_waitcnt vmcnt(0)" ::: "memory");
    __syncthreads();
    if (tid == 0) {
        __hip_atomic_store(&flags[bg * 8 + jgrp], 1u, __ATOMIC_RELAXED,
                           __HIP_MEMORY_SCOPE_AGENT);
    }

    const int r = tid >> 4;          // 0..15: staged h row
    const int c0 = (tid & 15) * 32;  // 32-u32 column chunk

    for (int t = 0; t < Lt; ++t) {
        // ---- wait for h_{t-1}: the 8 producer wgs of this bg ----
        {
            const unsigned tgt = (unsigned)t + 1u;
            while (true) {
                unsigned v = __hip_atomic_load(&flags[bg * 8 + (lane & 7)],
                                               __ATOMIC_RELAXED,
                                               __HIP_MEMORY_SCOPE_AGENT);
                if (__ballot(v >= tgt) == 0xFFFFFFFFFFFFFFFFull) break;
            }
        }

        // ---- xp tile loads (own 16x16 of out[t]); hide under staging+MFMA.
        // Disjoint j-columns per wg: no cross-wg hazard with the h_t write.
        float xpv[4];
        {
            const float* xr = out + (size_t)t * BH;
            #pragma unroll
            for (int rr = 0; rr < 4; ++rr)
                xpv[rr] = xr[(size_t)(b0 + quad * 4 + rr) * Hh + (j0 + rw)];
        }

        // ---- cooperative load + decode h_{t-1} into swizzled LDS hi/lo ----
        {
            const unsigned* hrow = hpk + (size_t)((t + 1) & 1) * BH +
                                   (size_t)(b0 + r) * Hh + c0;
            unsigned long long p[16];
            #pragma unroll
            for (int q = 0; q < 16; ++q)
                p[q] = __hip_atomic_load((const unsigned long long*)(hrow + 2 * q),
                                         __ATOMIC_RELAXED,
                                         __HIP_MEMORY_SCOPE_AGENT);
            #pragma unroll
            for (int g = 0; g < 4; ++g) {
                u32x4 Hq, Lq;
                #pragma unroll
                for (int e = 0; e < 4; ++e) {
                    unsigned a = (unsigned)p[g * 4 + e];
                    unsigned b = (unsigned)(p[g * 4 + e] >> 32);
                    Hq[e] = pack_hi16(a, b);
                    Lq[e] = pack_lo16(a, b);
                }
                int idx = swzi(r, c0 + g * 8);
                *(u32x4*)&HHi[idx] = Hq;
                *(u32x4*)&HLo[idx] = Lq;
            }
        }
        __syncthreads();

        // ---- h phase: h_{t-1} * Wh^T, B from VGPRs ----
        f32x4 aHH = {0.f, 0.f, 0.f, 0.f};
        f32x4 aHL = {0.f, 0.f, 0.f, 0.f};
        f32x4 aLH = {0.f, 0.f, 0.f, 0.f};
        #pragma unroll
        for (int c = 0; c < 16; ++c) {
            int kk = c * 32 + quad * 8;
            bf16x8 aH = __builtin_bit_cast(bf16x8, *(const u16x8*)&HHi[swzi(rw, kk)]);
            bf16x8 aL = __builtin_bit_cast(bf16x8, *(const u16x8*)&HLo[swzi(rw, kk)]);
            aHH = MFMA16(aH, whH[c], aHH, 0, 0, 0);
            aHL = MFMA16(aH, whL[c], aHL, 0, 0, 0);
            aLH = MFMA16(aL, whH[c], aLH, 0, 0, 0);
        }
        f32x4 acc = aHH + aHL + aLH;

        float hv[4];
        #pragma unroll
        for (int rr = 0; rr < 4; ++rr) hv[rr] = tanh_fast(acc[rr] + xpv[rr]);

        // ---- publish h_t ----
        unsigned* hw = hpk + (size_t)(t & 1) * BH;
        #pragma unroll
        for (int rr = 0; rr < 4; ++rr) {
            int b = b0 + quad * 4 + rr;
            unsigned u = __float_as_uint(hv[rr]);
            unsigned hb = u >> 16;
            unsigned lb =
                __float_as_uint(hv[rr] - __uint_as_float(u & 0xFFFF0000u)) >> 16;
            __hip_atomic_store(hw + (size_t)b * Hh + (j0 + rw), (hb << 16) | lb,
                               __ATOMIC_RELAXED, __HIP_MEMORY_SCOPE_AGENT);
        }
        asm volatile("s_waitcnt vmcnt(0)" ::: "memory");
        __syncthreads();  // all 4 waves' stores acked; also protects LDS reuse
        if (tid == 0 && t + 1 < Lt) {
            __hip_atomic_store(&flags[bg * 8 + jgrp], (unsigned)(t + 2),
                               __ATOMIC_RELAXED, __HIP_MEMORY_SCOPE_AGENT);
        }

        // out stores after the flag — not on anyone's critical path
        #pragma unroll
        for (int rr = 0; rr < 4; ++rr) {
            int b = b0 + quad * 4 + rr;
            out[((size_t)t * Bn + b) * Hh + (j0 + rw)] = hv[rr];
        }
        if (t == Lt - 1) {
            #pragma unroll
            for (int rr = 0; rr < 4; ++rr) {
                int b = b0 + quad * 4 + rr;
                out[(size_t)Lt * BH + (size_t)b * Hh + (j0 + rw)] = hv[rr];
            }
        }
    }
}

extern "C" void kernel_launch(void* const* d_in, const int* in_sizes, int n_in,
                              void* d_out, int out_size, void* d_ws, size_t ws_size,
                              hipStream_t stream) {
    const float* x    = (const float*)d_in[0];  // [L,B,D]
    const float* h0   = (const float*)d_in[1];  // [B,H]
    const float* Wx_w = (const float*)d_in[2];  // [H,D]
    const float* Wx_b = (const float*)d_in[3];  // [H]
    const float* Wh_w = (const float*)d_in[4];  // [H,H]
    const float* Wh_b = (const float*)d_in[5];  // [H]
    float* out = (float*)d_out;                 // hAll [L,B,H] ++ h_last [B,H]

    unsigned* hpk   = (unsigned*)d_ws;          // 2 x [B][H] packed (hi|lo), 512 KB
    unsigned* flags = hpk + 2 * BH;             // [8][8] monotonic counters

    zero_flags_kernel<<<1, 256, 0, stream>>>(flags);
    // Pass 1: xproj (+ both biases) into out[0 .. L*B*H)
    xproj_kernel<<<512, 256, 0, stream>>>(x, Wx_w, Wx_b, Wh_b, out);
    // Pass 2: recurrence, reads xp from out and overwrites with h_t
    rnn_rec4_kernel<<<64, 256, 0, stream>>>(h0, Wh_w, out, hpk, flags);
}